// Round 12
// baseline (31466.101 us; speedup 1.0000x reference)
//
#include <hip/hip_runtime.h>
#include <stdint.h>

#define NT 600
#define NMAIN 100
#define NWG 156
#define NAUX (NWG - NMAIN)

// ---- ws layout (bytes) ----
#define OFF_XTH  0          // [600][64][32]  f16  2457600
#define OFF_H1H  2457600    // [4][64][448]   f16  229376
#define OFF_H2H  2686976    // [2][64][448]   f16  114688
#define OFF_H3H  2801664    // [2][64][448]   f16  114688
#define OFF_WINH 2916352    // [2][64][128]   f16  32768
#define OFF_BC   2949120    // [3][1600]      f32  19200
#define OFF_GY   2968320    // [2][64][128]   f32  65536
#define OFF_CNT  3033856    // [12*32]        i32  2048

#define HROW 448
#define HSLOT 28672
#define WROW 128
#define WSLOT 8192
#define XROW 32
#define GYSLOT 8192

typedef _Float16 h2v __attribute__((ext_vector_type(2)));
typedef _Float16 f16x8 __attribute__((ext_vector_type(8)));
typedef float f32x4 __attribute__((ext_vector_type(4)));

struct Params {
  const float* x; const int* cs; const int* cl; const float* bias;
  const float *Wih1,*Whh1,*bih1,*bhh1,*Wih2,*Whh2,*bih2,*bhh2,*Wih3,*Whh3,*bih3,*bhh3;
  const float *Watt,*batt,*Wgmm,*bgmm;
  _Float16 *XTH,*H1H,*H2H,*H3H,*WINH;
  float *BC,*GY;
  int *CNT;
  float* out;
};

__device__ __forceinline__ float sigm(float x) { return 1.f / (1.f + expf(-x)); }

__device__ __forceinline__ float FDOT2(unsigned a, unsigned b, float c) {
#if __has_builtin(__builtin_amdgcn_fdot2)
  return __builtin_amdgcn_fdot2(__builtin_bit_cast(h2v, a), __builtin_bit_cast(h2v, b), c, false);
#else
  h2v x = __builtin_bit_cast(h2v, a), y = __builtin_bit_cast(h2v, b);
  return c + (float)x[0]*(float)y[0] + (float)x[1]*(float)y[1];
#endif
}

// relaxed agent-scope 4B accessors (sc0 sc1 -> LLC-coherent, no fences)
__device__ __forceinline__ unsigned ALu(const void* p) {
  return __hip_atomic_load((const unsigned*)p, __ATOMIC_RELAXED, __HIP_MEMORY_SCOPE_AGENT);
}
__device__ __forceinline__ float ALf(const void* p) {
  return __hip_atomic_load((const float*)p, __ATOMIC_RELAXED, __HIP_MEMORY_SCOPE_AGENT);
}
__device__ __forceinline__ void ASu(void* p, unsigned v) {
  __hip_atomic_store((unsigned*)p, v, __ATOMIC_RELAXED, __HIP_MEMORY_SCOPE_AGENT);
}
__device__ __forceinline__ void ASf(void* p, float v) {
  __hip_atomic_store((float*)p, v, __ATOMIC_RELAXED, __HIP_MEMORY_SCOPE_AGENT);
}
__device__ __forceinline__ uint4 ld_state16(const _Float16* p) {
  const unsigned* u = (const unsigned*)p;
  uint4 r;
  r.x = ALu(u + 0); r.y = ALu(u + 1); r.z = ALu(u + 2); r.w = ALu(u + 3);
  return r;
}

// 12-sub-counter barrier, ALL RELAXED (no wbl2/buffer_inv)
__device__ __forceinline__ void tbar(int* C, int w, int& ph) {
  __syncthreads();
  if (threadIdx.x == 0)
    __hip_atomic_fetch_add(&C[(w % 12)*32], 1, __ATOMIC_RELAXED, __HIP_MEMORY_SCOPE_AGENT);
  ++ph;
  const int tgt = 13*ph;
  if (threadIdx.x < 12) {
    while (__hip_atomic_load(&C[threadIdx.x*32], __ATOMIC_RELAXED, __HIP_MEMORY_SCOPE_AGENT) < tgt)
      __builtin_amdgcn_s_sleep(1);
  }
  __syncthreads();
}

// =====================  prep  =====================
__global__ void prep_k(Params P) {
  const long long NX  = 600LL*64*32;
  const long long NH1 = 4LL*64*448;
  const long long NH2 = 2LL*64*448;
  const long long NWH = 2LL*64*128;
  const long long NBc = 4800;
  const long long NCt = 512;
  const long long TOT = NX + NH1 + 2*NH2 + NWH + NBc + NCt;
  const long long stride = (long long)gridDim.x * blockDim.x;
  for (long long idx = (long long)blockIdx.x*blockDim.x + threadIdx.x; idx < TOT; idx += stride) {
    long long i = idx;
    if (i < NX) {
      int t = (int)(i >> 11);
      int rem = (int)(i & 2047);
      int b = rem >> 5, k = rem & 31;
      float v = (k < 3) ? P.x[((size_t)b*NT + t)*3 + k] : 0.f;
      P.XTH[i] = (_Float16)v;
      continue;
    }
    i -= NX;
    if (i < NH1) { P.H1H[i] = (_Float16)0.f; continue; } i -= NH1;
    if (i < NH2) { P.H2H[i] = (_Float16)0.f; continue; } i -= NH2;
    if (i < NH2) { P.H3H[i] = (_Float16)0.f; continue; } i -= NH2;
    if (i < NWH) { P.WINH[i] = (_Float16)0.f; continue; } i -= NWH;
    if (i < NBc) {
      int l = (int)(i / 1600), r = (int)(i % 1600);
      const float* bi = (l==0)?P.bih1:(l==1)?P.bih2:P.bih3;
      const float* bh = (l==0)?P.bhh1:(l==1)?P.bhh2:P.bhh3;
      P.BC[i] = bi[r] + bh[r];
      continue;
    }
    i -= NBc;
    P.CNT[i] = 0;
  }
}

// =====================  MFMA LSTM layer =====================
template<int L, int NBLK, int MAXI>
__device__ __forceinline__ void mfma_layer(const Params& P, const uint4* af,
    float* scr, float* gsum, const float* bcl, int w, int tt, float& cref, _Float16* Hout) {
  const int tid = threadIdx.x, ks = tid >> 6, l = tid & 63;
  uint4 bf[MAXI][4];
#pragma unroll
  for (int i = 0; i < MAXI; ++i) {
    const int kb = ks + 8*i;
    if (kb < NBLK) {
      const _Float16* bp; int k0, st; bool isx = false;
      if constexpr (L == 0) {
        if (kb < 4)       { bp = P.WINH + (size_t)((tt+1)&1)*WSLOT; st = WROW; k0 = kb*32; }
        else if (kb == 4) { bp = P.XTH + (size_t)tt*2048;           st = XROW; k0 = 0; isx = true; }
        else              { bp = P.H1H + (size_t)((tt+3)&3)*HSLOT;  st = HROW; k0 = (kb-5)*32; }
      } else if constexpr (L == 1) {
        if (kb == 0)      { bp = P.XTH + (size_t)tt*2048;           st = XROW; k0 = 0; isx = true; }
        else if (kb < 15) { bp = P.H1H + (size_t)(tt&3)*HSLOT;      st = HROW; k0 = (kb-1)*32; }
        else if (kb < 29) { bp = P.H2H + (size_t)((tt+1)&1)*HSLOT;  st = HROW; k0 = (kb-15)*32; }
        else              { bp = P.WINH + (size_t)(tt&1)*WSLOT;     st = WROW; k0 = (kb-29)*32; }
      } else {
        if (kb == 0)      { bp = P.XTH + (size_t)tt*2048;           st = XROW; k0 = 0; isx = true; }
        else if (kb < 15) { bp = P.H1H + (size_t)(tt&3)*HSLOT;      st = HROW; k0 = (kb-1)*32; }
        else if (kb < 29) { bp = P.H3H + (size_t)((tt+1)&1)*HSLOT;  st = HROW; k0 = (kb-15)*32; }
        else if (kb < 43) { bp = P.H2H + (size_t)(tt&1)*HSLOT;      st = HROW; k0 = (kb-29)*32; }
        else              { bp = P.WINH + (size_t)(tt&1)*WSLOT;     st = WROW; k0 = (kb-43)*32; }
      }
      const _Float16* base = bp + (size_t)(l & 15)*st + k0 + ((l >> 4)*8);
      if (isx) {
#pragma unroll
        for (int ct = 0; ct < 4; ++ct)
          bf[i][ct] = *(const uint4*)(base + (size_t)ct*16*st);
      } else {
#pragma unroll
        for (int ct = 0; ct < 4; ++ct)
          bf[i][ct] = ld_state16(base + (size_t)ct*16*st);
      }
    }
  }
  f32x4 acc[4] = {{0.f,0.f,0.f,0.f},{0.f,0.f,0.f,0.f},{0.f,0.f,0.f,0.f},{0.f,0.f,0.f,0.f}};
#pragma unroll
  for (int i = 0; i < MAXI; ++i) {
    const int kb = ks + 8*i;
    if (kb < NBLK) {
#pragma unroll
      for (int ct = 0; ct < 4; ++ct)
        acc[ct] = __builtin_amdgcn_mfma_f32_16x16x32_f16(
            __builtin_bit_cast(f16x8, af[i]), __builtin_bit_cast(f16x8, bf[i][ct]),
            acc[ct], 0, 0, 0);
    }
  }
  __syncthreads();
#pragma unroll
  for (int ct = 0; ct < 4; ++ct)
    *(f32x4*)&scr[((size_t)(ks*64 + ct*16 + (l & 15)))*21 + (l >> 4)*4] = acc[ct];
  __syncthreads();
#pragma unroll
  for (int p = 0; p < 2; ++p) {
    const int idx = tid + p*512, m = idx >> 6, b = idx & 63;
    float s = 0.f;
#pragma unroll
    for (int k = 0; k < 8; ++k) s += scr[(size_t)(k*64 + b)*21 + m];
    gsum[b*21 + m] = s + bcl[L*16 + m];
  }
  __syncthreads();
  if (tid < 256) {
    const int dd = tid >> 6, b = tid & 63;
    const float* gp = gsum + b*21 + dd*4;
    float c = sigm(gp[1])*cref + sigm(gp[0])*tanhf(gp[2]);
    cref = c;
    float h = sigm(gp[3])*tanhf(c);
    gsum[b*21 + 16 + dd] = h;           // stage for paired u32 store
  }
  __syncthreads();
  if (tid < 128) {
    const int d2 = tid >> 6, b = tid & 63;      // d2 = 0,1 -> dims (2*d2, 2*d2+1)
    _Float16 lo = (_Float16)gsum[b*21 + 16 + 2*d2];
    _Float16 hi = (_Float16)gsum[b*21 + 16 + 2*d2 + 1];
    h2v pk = { lo, hi };
    ASu(Hout + (size_t)b*HROW + 4*w + 2*d2, __builtin_bit_cast(unsigned, pk));
  }
}

// =====================  GMM via MFMA  =====================
__device__ __forceinline__ void gmm_mfma(const Params& P, const uint4* afg,
    float* scr, const float* bgl, int rlo, int tt) {
  const int tid = threadIdx.x, ks = tid >> 6, l = tid & 63;
  const _Float16* h1 = P.H1H + (size_t)(tt & 3)*HSLOT;
  const _Float16* h2 = P.H2H + (size_t)(tt & 1)*HSLOT;
  const _Float16* h3 = P.H3H + (size_t)(tt & 1)*HSLOT;
  uint4 bf[6][4];
#pragma unroll
  for (int i = 0; i < 6; ++i) {
    const int kb = ks + 8*i;
    if (kb < 42) {
      const _Float16* bp; int k0;
      if (kb < 14)      { bp = h1; k0 = kb*32; }
      else if (kb < 28) { bp = h2; k0 = (kb-14)*32; }
      else              { bp = h3; k0 = (kb-28)*32; }
      const _Float16* base = bp + (size_t)(l & 15)*HROW + k0 + ((l >> 4)*8);
#pragma unroll
      for (int ct = 0; ct < 4; ++ct)
        bf[i][ct] = ld_state16(base + (size_t)ct*16*HROW);
    }
  }
  f32x4 acc[4] = {{0.f,0.f,0.f,0.f},{0.f,0.f,0.f,0.f},{0.f,0.f,0.f,0.f},{0.f,0.f,0.f,0.f}};
#pragma unroll
  for (int i = 0; i < 6; ++i) {
    const int kb = ks + 8*i;
    if (kb < 42) {
#pragma unroll
      for (int ct = 0; ct < 4; ++ct)
        acc[ct] = __builtin_amdgcn_mfma_f32_16x16x32_f16(
            __builtin_bit_cast(f16x8, afg[i]), __builtin_bit_cast(f16x8, bf[i][ct]),
            acc[ct], 0, 0, 0);
    }
  }
  __syncthreads();
#pragma unroll
  for (int ct = 0; ct < 4; ++ct)
    *(f32x4*)&scr[((size_t)(ks*64 + ct*16 + (l & 15)))*17 + (l >> 4)*4] = acc[ct];
  __syncthreads();
  float* gy = P.GY + (size_t)(tt & 1)*GYSLOT;
#pragma unroll
  for (int p = 0; p < 2; ++p) {
    const int idx = tid + p*512, m = idx >> 6, b = idx & 63;
    float s = 0.f;
#pragma unroll
    for (int k = 0; k < 8; ++k) s += scr[(size_t)(k*64 + b)*17 + m];
    const int r = rlo + m;
    if (r < 121) ASf(&gy[b*128 + r], s + bgl[m]);
  }
  __syncthreads();
}

// attention window
__device__ __forceinline__ void att_do(const Params& P, const unsigned* WAPH, unsigned* h1p,
    float* parts, float* abk, float* kapl, float* phi, float* winl,
    const float* batl, const int* csl, const int* cll, int b, int lb, int t) {
  const int tid = threadIdx.x;
  const int s1 = t & 3, sw = t & 1;
  if (tid < 224)
    h1p[tid] = ALu((const unsigned*)(P.H1H + (size_t)s1*HSLOT + (size_t)b*HROW) + tid);
  __syncthreads();
  if (tid < 240) {
    int j = tid >> 3, pp = tid & 7;
    const unsigned* wr = WAPH + j*200 + pp*25;
    const unsigned* hr = h1p + pp*25;
    float acc = 0.f;
#pragma unroll
    for (int m = 0; m < 25; ++m) acc = FDOT2(hr[m], wr[m], acc);
    parts[tid] = acc;
  }
  __syncthreads();
  if (tid < 30) {
    float s = batl[tid];
#pragma unroll
    for (int pp = 0; pp < 8; ++pp) s += parts[tid*8 + pp];
    abk[tid] = expf(s);
  }
  __syncthreads();
  if (tid < 10) kapl[lb*10 + tid] += abk[20 + tid];
  __syncthreads();
  if (tid < 50) {
    float s = 0.f;
    if (tid < cll[lb]) {
#pragma unroll
      for (int k = 0; k < 10; ++k) {
        float dk = kapl[lb*10 + k] - (float)tid;
        s += abk[k]*expf(-abk[10 + k]*dk*dk);
      }
    }
    phi[tid] = s;
  }
  __syncthreads();
  if (tid < 77) {
    float s = 0.f;
    for (int u = 0; u < 50; ++u) s += (csl[lb*50 + u] == tid) ? phi[u] : 0.f;
    winl[tid] = s;
  }
  __syncthreads();
  if (tid < 64) {
    int a0 = 2*tid, a1 = 2*tid + 1;
    h2v pk = { (_Float16)((a0 < 77) ? winl[a0] : 0.f),
               (_Float16)((a1 < 77) ? winl[a1] : 0.f) };
    ASu(P.WINH + (size_t)sw*WSLOT + (size_t)b*WROW + a0, __builtin_bit_cast(unsigned, pk));
  }
  __syncthreads();
}

// y epilogue
__device__ __forceinline__ void yepi_do(const Params& P, const float* gy,
                                        float* rawl, float* smx, int b, int tt) {
  const int tid = threadIdx.x;
  __syncthreads();
  if (tid < 121) rawl[tid] = ALf(&gy[b*128 + tid]);
  __syncthreads();
  const float bia = P.bias[b];
  if (tid == 0) {
    float m = -1e30f;
    for (int j = 1; j <= 20; ++j) m = fmaxf(m, rawl[j]*(1.f + bia));
    float ss = 0.f;
    for (int j = 1; j <= 20; ++j) ss += expf(rawl[j]*(1.f + bia) - m);
    smx[0] = m; smx[1] = ss;
  }
  __syncthreads();
  float* yr = P.out + ((size_t)b*NT + tt)*121;
  if (tid == 0)           yr[120] = 1.f/(1.f + expf(-rawl[0]));
  else if (tid <= 20)     yr[tid - 1] = expf(rawl[tid]*(1.f + bia) - smx[0]) / smx[1];
  else if (tid <= 60)     yr[80 + tid - 21] = rawl[tid];
  else if (tid <= 100)    yr[20 + tid - 61] = expf(rawl[tid] - bia);
  else if (tid <= 120)    yr[60 + tid - 101] = tanhf(rawl[tid]);
  __syncthreads();
}

// =====================  persistent kernel: 156 WGs x 512 threads  =====================
__global__ __launch_bounds__(512, 1) void rnn_pers(Params P) {
  __shared__ __align__(16) char smem[69888];
  float* scr  = (float*)smem;                  // [8][64][21] f32
  float* gsum = (float*)(smem + 43008);        // [64][21] f32
  float* bcl  = (float*)(smem + 48384);        // 48 f32
  float* scrg = (float*)smem;                  // [8][64][17] f32 (aux q<8)
  unsigned* WAPH = (unsigned*)(smem + 39168);  // aux: Watt f16 pairs [30][200]
  float* M    = (float*)(smem + 63168);
  float* bgl  = M;
  float* parts= M + 16;
  float* abk  = M + 256;
  float* kapl = M + 286;
  float* phi  = M + 306;
  float* winl = M + 356;
  float* batl = M + 436;
  float* rawl = M + 466;
  float* smx  = M + 587;
  unsigned* h1p = (unsigned*)(M + 589);
  int*   csl  = (int*)(M + 813);
  int*   cll  = (int*)(M + 913);

  const int w = blockIdx.x, tid = threadIdx.x;
  const int ks = tid >> 6, l = tid & 63;
  int blo = 0, bhi = 0, ylo = 0, yhi = 0;
  uint4 af1[3], af2[5], af3[6], afg[6];

  if (w < NMAIN) {
    const int m = l & 15, dd = m >> 2, g = m & 3, gr = g*400 + 4*w + dd;
    const int kgo = (l >> 4)*8;
#pragma unroll
    for (int i = 0; i < 3; ++i) {
      const int kb = ks + 8*i;
      unsigned short u[8];
#pragma unroll
      for (int j = 0; j < 8; ++j) {
        float v = 0.f;
        if (kb < 19) {
          int kk = kb*32 + kgo + j;
          if (kk < 128)      { if (kk < 77) v = P.Wih1[(size_t)gr*80 + kk]; }
          else if (kk < 160) { int c = kk - 128; if (c < 3) v = P.Wih1[(size_t)gr*80 + 77 + c]; }
          else               { int c = kk - 160; if (c < 400) v = P.Whh1[(size_t)gr*400 + c]; }
        }
        u[j] = __builtin_bit_cast(unsigned short, (_Float16)v);
      }
      af1[i] = (uint4){(unsigned)u[0]|((unsigned)u[1]<<16), (unsigned)u[2]|((unsigned)u[3]<<16),
                       (unsigned)u[4]|((unsigned)u[5]<<16), (unsigned)u[6]|((unsigned)u[7]<<16)};
    }
#pragma unroll
    for (int i = 0; i < 5; ++i) {
      const int kb = ks + 8*i;
      unsigned short u[8];
#pragma unroll
      for (int j = 0; j < 8; ++j) {
        float v = 0.f;
        if (kb < 33) {
          int kk = kb*32 + kgo + j;
          if (kk < 32)       { if (kk < 3) v = P.Wih2[(size_t)gr*480 + kk]; }
          else if (kk < 480) { int c = kk - 32;  if (c < 400) v = P.Wih2[(size_t)gr*480 + 3 + c]; }
          else if (kk < 928) { int c = kk - 480; if (c < 400) v = P.Whh2[(size_t)gr*400 + c]; }
          else               { int c = kk - 928; if (c < 77)  v = P.Wih2[(size_t)gr*480 + 403 + c]; }
        }
        u[j] = __builtin_bit_cast(unsigned short, (_Float16)v);
      }
      af2[i] = (uint4){(unsigned)u[0]|((unsigned)u[1]<<16), (unsigned)u[2]|((unsigned)u[3]<<16),
                       (unsigned)u[4]|((unsigned)u[5]<<16), (unsigned)u[6]|((unsigned)u[7]<<16)};
    }
#pragma unroll
    for (int i = 0; i < 6; ++i) {
      const int kb = ks + 8*i;
      unsigned short u[8];
#pragma unroll
      for (int j = 0; j < 8; ++j) {
        float v = 0.f;
        if (kb < 47) {
          int kk = kb*32 + kgo + j;
          if (kk < 32)        { if (kk < 3) v = P.Wih3[(size_t)gr*880 + kk]; }
          else if (kk < 480)  { int c = kk - 32;   if (c < 400) v = P.Wih3[(size_t)gr*880 + 3 + c]; }
          else if (kk < 928)  { int c = kk - 480;  if (c < 400) v = P.Whh3[(size_t)gr*400 + c]; }
          else if (kk < 1376) { int c = kk - 928;  if (c < 400) v = P.Wih3[(size_t)gr*880 + 403 + c]; }
          else                { int c = kk - 1376; if (c < 77)  v = P.Wih3[(size_t)gr*880 + 803 + c]; }
        }
        u[j] = __builtin_bit_cast(unsigned short, (_Float16)v);
      }
      af3[i] = (uint4){(unsigned)u[0]|((unsigned)u[1]<<16), (unsigned)u[2]|((unsigned)u[3]<<16),
                       (unsigned)u[4]|((unsigned)u[5]<<16), (unsigned)u[6]|((unsigned)u[7]<<16)};
    }
    if (tid < 48) {
      int L = tid >> 4, mm = tid & 15, ddb = mm >> 2, gb = mm & 3;
      bcl[tid] = P.BC[L*1600 + gb*400 + 4*w + ddb];
    }
  } else {
    const int q = w - NMAIN;
    blo = (64*q)/NAUX;  bhi = (64*(q+1))/NAUX;
    if (q >= 8) { ylo = (64*(q-8))/48; yhi = (64*(q-7))/48; }
    if (q < 8) {
      const int m = l & 15, gr = q*16 + m;
      const int kgo = (l >> 4)*8;
#pragma unroll
      for (int i = 0; i < 6; ++i) {
        const int kb = ks + 8*i;
        unsigned short u[8];
#pragma unroll
        for (int j = 0; j < 8; ++j) {
          float v = 0.f;
          if (kb < 42 && gr < 121) {
            int kk = kb*32 + kgo + j;
            if (kk < 448)      { if (kk < 400) v = P.Wgmm[(size_t)gr*1200 + kk]; }
            else if (kk < 896) { int c = kk - 448; if (c < 400) v = P.Wgmm[(size_t)gr*1200 + 400 + c]; }
            else               { int c = kk - 896; if (c < 400) v = P.Wgmm[(size_t)gr*1200 + 800 + c]; }
          }
          u[j] = __builtin_bit_cast(unsigned short, (_Float16)v);
        }
        afg[i] = (uint4){(unsigned)u[0]|((unsigned)u[1]<<16), (unsigned)u[2]|((unsigned)u[3]<<16),
                         (unsigned)u[4]|((unsigned)u[5]<<16), (unsigned)u[6]|((unsigned)u[7]<<16)};
      }
      if (tid < 16) bgl[tid] = (q*16 + tid < 121) ? P.bgmm[q*16 + tid] : 0.f;
    }
    for (int i = tid; i < 6000; i += 512) {
      int j = i / 200, pr = i % 200;
      h2v pk = { (_Float16)P.Watt[j*400 + 2*pr], (_Float16)P.Watt[j*400 + 2*pr + 1] };
      WAPH[i] = __builtin_bit_cast(unsigned, pk);
    }
    if (tid < 30) batl[tid] = P.batt[tid];
    for (int lb = 0; lb < bhi - blo; ++lb) {
      if (tid < 50) csl[lb*50 + tid] = P.cs[(blo + lb)*50 + tid];
      if (tid == 0) cll[lb] = P.cl[blo + lb];
    }
    if (tid < 20) kapl[tid] = 0.f;
  }
  __syncthreads();

  int ph = 0;
  float c1 = 0.f, c2 = 0.f, c3 = 0.f;
  for (int t = 0; t <= NT + 2; ++t) {
    const bool doL1 = (t < NT), doL23 = (t >= 1 && t <= NT);
    const bool doG = (t >= 2 && t <= NT + 1), doY = (t >= 3);
    // Phase A: L1(t)+L2(t-1) mains || GMM(t-2) aux<8 | yepi(t-3) aux>=8
    if (w < NMAIN) {
      if (doL1)  mfma_layer<0, 19, 3>(P, af1, scr, gsum, bcl, w, t,     c1,
                                      P.H1H + (size_t)(t & 3)*HSLOT);
      if (doL23) mfma_layer<1, 33, 5>(P, af2, scr, gsum, bcl, w, t - 1, c2,
                                      P.H2H + (size_t)((t - 1) & 1)*HSLOT);
    } else {
      const int q = w - NMAIN;
      if (q < 8) {
        if (doG) gmm_mfma(P, afg, scrg, bgl, q*16, t - 2);
      } else if (doY) {
        const float* gy = P.GY + (size_t)((t - 3) & 1)*GYSLOT;
        for (int yb = ylo; yb < yhi; ++yb)
          yepi_do(P, gy, rawl, smx, yb, t - 3);
      }
    }
    tbar(P.CNT, w, ph);
    // Phase B: L3(t-1) mains || att(t) aux
    if (w < NMAIN) {
      if (doL23) mfma_layer<2, 47, 6>(P, af3, scr, gsum, bcl, w, t - 1, c3,
                                      P.H3H + (size_t)((t - 1) & 1)*HSLOT);
    } else {
      if (doL1)
        for (int lb = 0; lb < bhi - blo; ++lb)
          att_do(P, WAPH, h1p, parts, abk, kapl, phi, winl, batl, csl, cll, blo + lb, lb, t);
    }
    tbar(P.CNT, w, ph);
  }
}

extern "C" void kernel_launch(void* const* d_in, const int* in_sizes, int n_in,
                              void* d_out, int out_size, void* d_ws, size_t ws_size,
                              hipStream_t stream) {
  (void)in_sizes; (void)n_in; (void)out_size; (void)ws_size;
  Params P;
  P.x    = (const float*)d_in[0];
  P.cs   = (const int*)d_in[1];
  P.cl   = (const int*)d_in[2];
  P.bias = (const float*)d_in[3];
  P.Wih1 = (const float*)d_in[4];  P.Whh1 = (const float*)d_in[5];
  P.bih1 = (const float*)d_in[6];  P.bhh1 = (const float*)d_in[7];
  P.Wih2 = (const float*)d_in[8];  P.Whh2 = (const float*)d_in[9];
  P.bih2 = (const float*)d_in[10]; P.bhh2 = (const float*)d_in[11];
  P.Wih3 = (const float*)d_in[12]; P.Whh3 = (const float*)d_in[13];
  P.bih3 = (const float*)d_in[14]; P.bhh3 = (const float*)d_in[15];
  P.Watt = (const float*)d_in[16]; P.batt = (const float*)d_in[17];
  P.Wgmm = (const float*)d_in[18]; P.bgmm = (const float*)d_in[19];
  char* ws = (char*)d_ws;
  P.XTH  = (_Float16*)(ws + OFF_XTH);
  P.H1H  = (_Float16*)(ws + OFF_H1H);
  P.H2H  = (_Float16*)(ws + OFF_H2H);
  P.H3H  = (_Float16*)(ws + OFF_H3H);
  P.WINH = (_Float16*)(ws + OFF_WINH);
  P.BC   = (float*)(ws + OFF_BC);
  P.GY   = (float*)(ws + OFF_GY);
  P.CNT  = (int*)(ws + OFF_CNT);
  P.out  = (float*)d_out;

  hipLaunchKernelGGL(prep_k, dim3(1024), dim3(256), 0, stream, P);
  hipLaunchKernelGGL(rnn_pers, dim3(NWG), dim3(512), 0, stream, P);
}

// Round 13
// 14550.545 us; speedup vs baseline: 2.1625x; 2.1625x over previous
//
#include <hip/hip_runtime.h>
#include <stdint.h>

#define NT 600
#define NMAIN 100
#define NWG 156
#define NAUX (NWG - NMAIN)

// ---- ws layout (bytes) ----
#define OFF_XTH  0          // [600][64][32]  f16  2457600
#define OFF_H1H  2457600    // [4][64][448]   f16  229376
#define OFF_H2H  2686976    // [2][64][448]   f16  114688
#define OFF_H3H  2801664    // [2][64][448]   f16  114688
#define OFF_WINH 2916352    // [2][64][128]   f16  32768
#define OFF_BC   2949120    // [3][1600]      f32  19200
#define OFF_GY   2968320    // [2][64][128]   f32  65536
#define OFF_CNT  3033856    // [12*32]        i32  2048

#define HROW 448
#define HSLOT 28672
#define WROW 128
#define WSLOT 8192
#define XROW 32
#define GYSLOT 8192

typedef _Float16 h2v __attribute__((ext_vector_type(2)));
typedef _Float16 f16x8 __attribute__((ext_vector_type(8)));
typedef float f32x4 __attribute__((ext_vector_type(4)));
typedef unsigned u32x4 __attribute__((ext_vector_type(4)));

struct Params {
  const float* x; const int* cs; const int* cl; const float* bias;
  const float *Wih1,*Whh1,*bih1,*bhh1,*Wih2,*Whh2,*bih2,*bhh2,*Wih3,*Whh3,*bih3,*bhh3;
  const float *Watt,*batt,*Wgmm,*bgmm;
  _Float16 *XTH,*H1H,*H2H,*H3H,*WINH;
  float *BC,*GY;
  int *CNT;
  float* out;
};

__device__ __forceinline__ float sigm(float x) { return 1.f / (1.f + expf(-x)); }

__device__ __forceinline__ float FDOT2(unsigned a, unsigned b, float c) {
#if __has_builtin(__builtin_amdgcn_fdot2)
  return __builtin_amdgcn_fdot2(__builtin_bit_cast(h2v, a), __builtin_bit_cast(h2v, b), c, false);
#else
  h2v x = __builtin_bit_cast(h2v, a), y = __builtin_bit_cast(h2v, b);
  return c + (float)x[0]*(float)y[0] + (float)x[1]*(float)y[1];
#endif
}

// relaxed agent-scope 4B accessors (sc0 sc1 -> LLC write-through / coherent read)
__device__ __forceinline__ unsigned ALu(const void* p) {
  return __hip_atomic_load((const unsigned*)p, __ATOMIC_RELAXED, __HIP_MEMORY_SCOPE_AGENT);
}
__device__ __forceinline__ float ALf(const void* p) {
  return __hip_atomic_load((const float*)p, __ATOMIC_RELAXED, __HIP_MEMORY_SCOPE_AGENT);
}
__device__ __forceinline__ void ASu(void* p, unsigned v) {
  __hip_atomic_store((unsigned*)p, v, __ATOMIC_RELAXED, __HIP_MEMORY_SCOPE_AGENT);
}
__device__ __forceinline__ void ASf(void* p, float v) {
  __hip_atomic_store((float*)p, v, __ATOMIC_RELAXED, __HIP_MEMORY_SCOPE_AGENT);
}

// LLC-coherent 4x16B vector loads (batched, one vmcnt(0) per group of 4)
__device__ __forceinline__ void ld4x16_llc(const _Float16* base, size_t stride16, u32x4* out) {
  const _Float16* p0 = base;
  const _Float16* p1 = base + stride16;
  const _Float16* p2 = base + 2*stride16;
  const _Float16* p3 = base + 3*stride16;
  asm volatile(
    "global_load_dwordx4 %0, %4, off sc0 sc1\n\t"
    "global_load_dwordx4 %1, %5, off sc0 sc1\n\t"
    "global_load_dwordx4 %2, %6, off sc0 sc1\n\t"
    "global_load_dwordx4 %3, %7, off sc0 sc1\n\t"
    "s_waitcnt vmcnt(0)"
    : "=&v"(out[0]), "=&v"(out[1]), "=&v"(out[2]), "=&v"(out[3])
    : "v"(p0), "v"(p1), "v"(p2), "v"(p3)
    : "memory");
}

// 12-sub-counter barrier, ALL RELAXED (no wbl2/buffer_inv)
__device__ __forceinline__ void tbar(int* C, int w, int& ph) {
  __syncthreads();
  if (threadIdx.x == 0)
    __hip_atomic_fetch_add(&C[(w % 12)*32], 1, __ATOMIC_RELAXED, __HIP_MEMORY_SCOPE_AGENT);
  ++ph;
  const int tgt = 13*ph;
  if (threadIdx.x < 12) {
    while (__hip_atomic_load(&C[threadIdx.x*32], __ATOMIC_RELAXED, __HIP_MEMORY_SCOPE_AGENT) < tgt)
      __builtin_amdgcn_s_sleep(1);
  }
  __syncthreads();
}

// =====================  prep  =====================
__global__ void prep_k(Params P) {
  const long long NX  = 600LL*64*32;
  const long long NH1 = 4LL*64*448;
  const long long NH2 = 2LL*64*448;
  const long long NWH = 2LL*64*128;
  const long long NBc = 4800;
  const long long NCt = 512;
  const long long TOT = NX + NH1 + 2*NH2 + NWH + NBc + NCt;
  const long long stride = (long long)gridDim.x * blockDim.x;
  for (long long idx = (long long)blockIdx.x*blockDim.x + threadIdx.x; idx < TOT; idx += stride) {
    long long i = idx;
    if (i < NX) {
      int t = (int)(i >> 11);
      int rem = (int)(i & 2047);
      int b = rem >> 5, k = rem & 31;
      float v = (k < 3) ? P.x[((size_t)b*NT + t)*3 + k] : 0.f;
      P.XTH[i] = (_Float16)v;
      continue;
    }
    i -= NX;
    if (i < NH1) { P.H1H[i] = (_Float16)0.f; continue; } i -= NH1;
    if (i < NH2) { P.H2H[i] = (_Float16)0.f; continue; } i -= NH2;
    if (i < NH2) { P.H3H[i] = (_Float16)0.f; continue; } i -= NH2;
    if (i < NWH) { P.WINH[i] = (_Float16)0.f; continue; } i -= NWH;
    if (i < NBc) {
      int l = (int)(i / 1600), r = (int)(i % 1600);
      const float* bi = (l==0)?P.bih1:(l==1)?P.bih2:P.bih3;
      const float* bh = (l==0)?P.bhh1:(l==1)?P.bhh2:P.bhh3;
      P.BC[i] = bi[r] + bh[r];
      continue;
    }
    i -= NBc;
    P.CNT[i] = 0;
  }
}

// =====================  MFMA LSTM layer =====================
template<int L, int NBLK, int MAXI>
__device__ __forceinline__ void mfma_layer(const Params& P, const u32x4* af,
    float* scr, float* gsum, const float* bcl, int w, int tt, float& cref, _Float16* Hout) {
  const int tid = threadIdx.x, ks = tid >> 6, l = tid & 63;
  u32x4 bf[MAXI][4];
#pragma unroll
  for (int i = 0; i < MAXI; ++i) {
    const int kb = ks + 8*i;
    if (kb < NBLK) {
      const _Float16* bp; int k0, st; bool isx = false;
      if constexpr (L == 0) {
        if (kb < 4)       { bp = P.WINH + (size_t)((tt+1)&1)*WSLOT; st = WROW; k0 = kb*32; }
        else if (kb == 4) { bp = P.XTH + (size_t)tt*2048;           st = XROW; k0 = 0; isx = true; }
        else              { bp = P.H1H + (size_t)((tt+3)&3)*HSLOT;  st = HROW; k0 = (kb-5)*32; }
      } else if constexpr (L == 1) {
        if (kb == 0)      { bp = P.XTH + (size_t)tt*2048;           st = XROW; k0 = 0; isx = true; }
        else if (kb < 15) { bp = P.H1H + (size_t)(tt&3)*HSLOT;      st = HROW; k0 = (kb-1)*32; }
        else if (kb < 29) { bp = P.H2H + (size_t)((tt+1)&1)*HSLOT;  st = HROW; k0 = (kb-15)*32; }
        else              { bp = P.WINH + (size_t)(tt&1)*WSLOT;     st = WROW; k0 = (kb-29)*32; }
      } else {
        if (kb == 0)      { bp = P.XTH + (size_t)tt*2048;           st = XROW; k0 = 0; isx = true; }
        else if (kb < 15) { bp = P.H1H + (size_t)(tt&3)*HSLOT;      st = HROW; k0 = (kb-1)*32; }
        else if (kb < 29) { bp = P.H3H + (size_t)((tt+1)&1)*HSLOT;  st = HROW; k0 = (kb-15)*32; }
        else if (kb < 43) { bp = P.H2H + (size_t)(tt&1)*HSLOT;      st = HROW; k0 = (kb-29)*32; }
        else              { bp = P.WINH + (size_t)(tt&1)*WSLOT;     st = WROW; k0 = (kb-43)*32; }
      }
      const _Float16* base = bp + (size_t)(l & 15)*st + k0 + ((l >> 4)*8);
      if (isx) {
#pragma unroll
        for (int ct = 0; ct < 4; ++ct)
          bf[i][ct] = *(const u32x4*)(base + (size_t)ct*16*st);
      } else {
        ld4x16_llc(base, (size_t)16*st, bf[i]);
      }
    }
  }
  f32x4 acc[4] = {{0.f,0.f,0.f,0.f},{0.f,0.f,0.f,0.f},{0.f,0.f,0.f,0.f},{0.f,0.f,0.f,0.f}};
#pragma unroll
  for (int i = 0; i < MAXI; ++i) {
    const int kb = ks + 8*i;
    if (kb < NBLK) {
#pragma unroll
      for (int ct = 0; ct < 4; ++ct)
        acc[ct] = __builtin_amdgcn_mfma_f32_16x16x32_f16(
            __builtin_bit_cast(f16x8, af[i]), __builtin_bit_cast(f16x8, bf[i][ct]),
            acc[ct], 0, 0, 0);
    }
  }
  __syncthreads();
#pragma unroll
  for (int ct = 0; ct < 4; ++ct)
    *(f32x4*)&scr[((size_t)(ks*64 + ct*16 + (l & 15)))*21 + (l >> 4)*4] = acc[ct];
  __syncthreads();
#pragma unroll
  for (int p = 0; p < 2; ++p) {
    const int idx = tid + p*512, m = idx >> 6, b = idx & 63;
    float s = 0.f;
#pragma unroll
    for (int k = 0; k < 8; ++k) s += scr[(size_t)(k*64 + b)*21 + m];
    gsum[b*21 + m] = s + bcl[L*16 + m];
  }
  __syncthreads();
  if (tid < 256) {
    const int dd = tid >> 6, b = tid & 63;
    const float* gp = gsum + b*21 + dd*4;
    float c = sigm(gp[1])*cref + sigm(gp[0])*tanhf(gp[2]);
    cref = c;
    float h = sigm(gp[3])*tanhf(c);
    gsum[b*21 + 16 + dd] = h;           // stage for paired u32 store
  }
  __syncthreads();
  if (tid < 128) {
    const int d2 = tid >> 6, b = tid & 63;      // d2 = 0,1 -> dims (2*d2, 2*d2+1)
    _Float16 lo = (_Float16)gsum[b*21 + 16 + 2*d2];
    _Float16 hi = (_Float16)gsum[b*21 + 16 + 2*d2 + 1];
    h2v pk = { lo, hi };
    ASu(Hout + (size_t)b*HROW + 4*w + 2*d2, __builtin_bit_cast(unsigned, pk));
  }
}

// =====================  GMM via MFMA  =====================
__device__ __forceinline__ void gmm_mfma(const Params& P, const u32x4* afg,
    float* scr, const float* bgl, int rlo, int tt) {
  const int tid = threadIdx.x, ks = tid >> 6, l = tid & 63;
  const _Float16* h1 = P.H1H + (size_t)(tt & 3)*HSLOT;
  const _Float16* h2 = P.H2H + (size_t)(tt & 1)*HSLOT;
  const _Float16* h3 = P.H3H + (size_t)(tt & 1)*HSLOT;
  u32x4 bf[6][4];
#pragma unroll
  for (int i = 0; i < 6; ++i) {
    const int kb = ks + 8*i;
    if (kb < 42) {
      const _Float16* bp; int k0;
      if (kb < 14)      { bp = h1; k0 = kb*32; }
      else if (kb < 28) { bp = h2; k0 = (kb-14)*32; }
      else              { bp = h3; k0 = (kb-28)*32; }
      const _Float16* base = bp + (size_t)(l & 15)*HROW + k0 + ((l >> 4)*8);
      ld4x16_llc(base, (size_t)16*HROW, bf[i]);
    }
  }
  f32x4 acc[4] = {{0.f,0.f,0.f,0.f},{0.f,0.f,0.f,0.f},{0.f,0.f,0.f,0.f},{0.f,0.f,0.f,0.f}};
#pragma unroll
  for (int i = 0; i < 6; ++i) {
    const int kb = ks + 8*i;
    if (kb < 42) {
#pragma unroll
      for (int ct = 0; ct < 4; ++ct)
        acc[ct] = __builtin_amdgcn_mfma_f32_16x16x32_f16(
            __builtin_bit_cast(f16x8, afg[i]), __builtin_bit_cast(f16x8, bf[i][ct]),
            acc[ct], 0, 0, 0);
    }
  }
  __syncthreads();
#pragma unroll
  for (int ct = 0; ct < 4; ++ct)
    *(f32x4*)&scr[((size_t)(ks*64 + ct*16 + (l & 15)))*17 + (l >> 4)*4] = acc[ct];
  __syncthreads();
  float* gy = P.GY + (size_t)(tt & 1)*GYSLOT;
#pragma unroll
  for (int p = 0; p < 2; ++p) {
    const int idx = tid + p*512, m = idx >> 6, b = idx & 63;
    float s = 0.f;
#pragma unroll
    for (int k = 0; k < 8; ++k) s += scr[(size_t)(k*64 + b)*17 + m];
    const int r = rlo + m;
    if (r < 121) ASf(&gy[b*128 + r], s + bgl[m]);
  }
  __syncthreads();
}

// attention window
__device__ __forceinline__ void att_do(const Params& P, const unsigned* WAPH, unsigned* h1p,
    float* parts, float* abk, float* kapl, float* phi, float* winl,
    const float* batl, const int* csl, const int* cll, int b, int lb, int t) {
  const int tid = threadIdx.x;
  const int s1 = t & 3, sw = t & 1;
  if (tid < 224)
    h1p[tid] = ALu((const unsigned*)(P.H1H + (size_t)s1*HSLOT + (size_t)b*HROW) + tid);
  __syncthreads();
  if (tid < 240) {
    int j = tid >> 3, pp = tid & 7;
    const unsigned* wr = WAPH + j*200 + pp*25;
    const unsigned* hr = h1p + pp*25;
    float acc = 0.f;
#pragma unroll
    for (int m = 0; m < 25; ++m) acc = FDOT2(hr[m], wr[m], acc);
    parts[tid] = acc;
  }
  __syncthreads();
  if (tid < 30) {
    float s = batl[tid];
#pragma unroll
    for (int pp = 0; pp < 8; ++pp) s += parts[tid*8 + pp];
    abk[tid] = expf(s);
  }
  __syncthreads();
  if (tid < 10) kapl[lb*10 + tid] += abk[20 + tid];
  __syncthreads();
  if (tid < 50) {
    float s = 0.f;
    if (tid < cll[lb]) {
#pragma unroll
      for (int k = 0; k < 10; ++k) {
        float dk = kapl[lb*10 + k] - (float)tid;
        s += abk[k]*expf(-abk[10 + k]*dk*dk);
      }
    }
    phi[tid] = s;
  }
  __syncthreads();
  if (tid < 77) {
    float s = 0.f;
    for (int u = 0; u < 50; ++u) s += (csl[lb*50 + u] == tid) ? phi[u] : 0.f;
    winl[tid] = s;
  }
  __syncthreads();
  if (tid < 64) {
    int a0 = 2*tid, a1 = 2*tid + 1;
    h2v pk = { (_Float16)((a0 < 77) ? winl[a0] : 0.f),
               (_Float16)((a1 < 77) ? winl[a1] : 0.f) };
    ASu(P.WINH + (size_t)sw*WSLOT + (size_t)b*WROW + a0, __builtin_bit_cast(unsigned, pk));
  }
  __syncthreads();
}

// y epilogue
__device__ __forceinline__ void yepi_do(const Params& P, const float* gy,
                                        float* rawl, float* smx, int b, int tt) {
  const int tid = threadIdx.x;
  __syncthreads();
  if (tid < 121) rawl[tid] = ALf(&gy[b*128 + tid]);
  __syncthreads();
  const float bia = P.bias[b];
  if (tid == 0) {
    float m = -1e30f;
    for (int j = 1; j <= 20; ++j) m = fmaxf(m, rawl[j]*(1.f + bia));
    float ss = 0.f;
    for (int j = 1; j <= 20; ++j) ss += expf(rawl[j]*(1.f + bia) - m);
    smx[0] = m; smx[1] = ss;
  }
  __syncthreads();
  float* yr = P.out + ((size_t)b*NT + tt)*121;
  if (tid == 0)           yr[120] = 1.f/(1.f + expf(-rawl[0]));
  else if (tid <= 20)     yr[tid - 1] = expf(rawl[tid]*(1.f + bia) - smx[0]) / smx[1];
  else if (tid <= 60)     yr[80 + tid - 21] = rawl[tid];
  else if (tid <= 100)    yr[20 + tid - 61] = expf(rawl[tid] - bia);
  else if (tid <= 120)    yr[60 + tid - 101] = tanhf(rawl[tid]);
  __syncthreads();
}

// =====================  persistent kernel: 156 WGs x 512 threads  =====================
__global__ __launch_bounds__(512, 1) void rnn_pers(Params P) {
  __shared__ __align__(16) char smem[69888];
  float* scr  = (float*)smem;                  // [8][64][21] f32
  float* gsum = (float*)(smem + 43008);        // [64][21] f32
  float* bcl  = (float*)(smem + 48384);        // 48 f32
  float* scrg = (float*)smem;                  // [8][64][17] f32 (aux q<8)
  unsigned* WAPH = (unsigned*)(smem + 39168);  // aux: Watt f16 pairs [30][200]
  float* M    = (float*)(smem + 63168);
  float* bgl  = M;
  float* parts= M + 16;
  float* abk  = M + 256;
  float* kapl = M + 286;
  float* phi  = M + 306;
  float* winl = M + 356;
  float* batl = M + 436;
  float* rawl = M + 466;
  float* smx  = M + 587;
  unsigned* h1p = (unsigned*)(M + 589);
  int*   csl  = (int*)(M + 813);
  int*   cll  = (int*)(M + 913);

  const int w = blockIdx.x, tid = threadIdx.x;
  const int ks = tid >> 6, l = tid & 63;
  int blo = 0, bhi = 0, ylo = 0, yhi = 0;
  u32x4 af1[3], af2[5], af3[6], afg[6];

  if (w < NMAIN) {
    const int m = l & 15, dd = m >> 2, g = m & 3, gr = g*400 + 4*w + dd;
    const int kgo = (l >> 4)*8;
#pragma unroll
    for (int i = 0; i < 3; ++i) {
      const int kb = ks + 8*i;
      unsigned short u[8];
#pragma unroll
      for (int j = 0; j < 8; ++j) {
        float v = 0.f;
        if (kb < 19) {
          int kk = kb*32 + kgo + j;
          if (kk < 128)      { if (kk < 77) v = P.Wih1[(size_t)gr*80 + kk]; }
          else if (kk < 160) { int c = kk - 128; if (c < 3) v = P.Wih1[(size_t)gr*80 + 77 + c]; }
          else               { int c = kk - 160; if (c < 400) v = P.Whh1[(size_t)gr*400 + c]; }
        }
        u[j] = __builtin_bit_cast(unsigned short, (_Float16)v);
      }
      af1[i] = (u32x4){(unsigned)u[0]|((unsigned)u[1]<<16), (unsigned)u[2]|((unsigned)u[3]<<16),
                       (unsigned)u[4]|((unsigned)u[5]<<16), (unsigned)u[6]|((unsigned)u[7]<<16)};
    }
#pragma unroll
    for (int i = 0; i < 5; ++i) {
      const int kb = ks + 8*i;
      unsigned short u[8];
#pragma unroll
      for (int j = 0; j < 8; ++j) {
        float v = 0.f;
        if (kb < 33) {
          int kk = kb*32 + kgo + j;
          if (kk < 32)       { if (kk < 3) v = P.Wih2[(size_t)gr*480 + kk]; }
          else if (kk < 480) { int c = kk - 32;  if (c < 400) v = P.Wih2[(size_t)gr*480 + 3 + c]; }
          else if (kk < 928) { int c = kk - 480; if (c < 400) v = P.Whh2[(size_t)gr*400 + c]; }
          else               { int c = kk - 928; if (c < 77)  v = P.Wih2[(size_t)gr*480 + 403 + c]; }
        }
        u[j] = __builtin_bit_cast(unsigned short, (_Float16)v);
      }
      af2[i] = (u32x4){(unsigned)u[0]|((unsigned)u[1]<<16), (unsigned)u[2]|((unsigned)u[3]<<16),
                       (unsigned)u[4]|((unsigned)u[5]<<16), (unsigned)u[6]|((unsigned)u[7]<<16)};
    }
#pragma unroll
    for (int i = 0; i < 6; ++i) {
      const int kb = ks + 8*i;
      unsigned short u[8];
#pragma unroll
      for (int j = 0; j < 8; ++j) {
        float v = 0.f;
        if (kb < 47) {
          int kk = kb*32 + kgo + j;
          if (kk < 32)        { if (kk < 3) v = P.Wih3[(size_t)gr*880 + kk]; }
          else if (kk < 480)  { int c = kk - 32;   if (c < 400) v = P.Wih3[(size_t)gr*880 + 3 + c]; }
          else if (kk < 928)  { int c = kk - 480;  if (c < 400) v = P.Whh3[(size_t)gr*400 + c]; }
          else if (kk < 1376) { int c = kk - 928;  if (c < 400) v = P.Wih3[(size_t)gr*880 + 403 + c]; }
          else                { int c = kk - 1376; if (c < 77)  v = P.Wih3[(size_t)gr*880 + 803 + c]; }
        }
        u[j] = __builtin_bit_cast(unsigned short, (_Float16)v);
      }
      af3[i] = (u32x4){(unsigned)u[0]|((unsigned)u[1]<<16), (unsigned)u[2]|((unsigned)u[3]<<16),
                       (unsigned)u[4]|((unsigned)u[5]<<16), (unsigned)u[6]|((unsigned)u[7]<<16)};
    }
    if (tid < 48) {
      int L = tid >> 4, mm = tid & 15, ddb = mm >> 2, gb = mm & 3;
      bcl[tid] = P.BC[L*1600 + gb*400 + 4*w + ddb];
    }
  } else {
    const int q = w - NMAIN;
    blo = (64*q)/NAUX;  bhi = (64*(q+1))/NAUX;
    if (q >= 8) { ylo = (64*(q-8))/48; yhi = (64*(q-7))/48; }
    if (q < 8) {
      const int m = l & 15, gr = q*16 + m;
      const int kgo = (l >> 4)*8;
#pragma unroll
      for (int i = 0; i < 6; ++i) {
        const int kb = ks + 8*i;
        unsigned short u[8];
#pragma unroll
        for (int j = 0; j < 8; ++j) {
          float v = 0.f;
          if (kb < 42 && gr < 121) {
            int kk = kb*32 + kgo + j;
            if (kk < 448)      { if (kk < 400) v = P.Wgmm[(size_t)gr*1200 + kk]; }
            else if (kk < 896) { int c = kk - 448; if (c < 400) v = P.Wgmm[(size_t)gr*1200 + 400 + c]; }
            else               { int c = kk - 896; if (c < 400) v = P.Wgmm[(size_t)gr*1200 + 800 + c]; }
          }
          u[j] = __builtin_bit_cast(unsigned short, (_Float16)v);
        }
        afg[i] = (u32x4){(unsigned)u[0]|((unsigned)u[1]<<16), (unsigned)u[2]|((unsigned)u[3]<<16),
                         (unsigned)u[4]|((unsigned)u[5]<<16), (unsigned)u[6]|((unsigned)u[7]<<16)};
      }
      if (tid < 16) bgl[tid] = (q*16 + tid < 121) ? P.bgmm[q*16 + tid] : 0.f;
    }
    for (int i = tid; i < 6000; i += 512) {
      int j = i / 200, pr = i % 200;
      h2v pk = { (_Float16)P.Watt[j*400 + 2*pr], (_Float16)P.Watt[j*400 + 2*pr + 1] };
      WAPH[i] = __builtin_bit_cast(unsigned, pk);
    }
    if (tid < 30) batl[tid] = P.batt[tid];
    for (int lb = 0; lb < bhi - blo; ++lb) {
      if (tid < 50) csl[lb*50 + tid] = P.cs[(blo + lb)*50 + tid];
      if (tid == 0) cll[lb] = P.cl[blo + lb];
    }
    if (tid < 20) kapl[tid] = 0.f;
  }
  __syncthreads();

  int ph = 0;
  float c1 = 0.f, c2 = 0.f, c3 = 0.f;
  for (int t = 0; t <= NT + 2; ++t) {
    const bool doL1 = (t < NT), doL23 = (t >= 1 && t <= NT);
    const bool doG = (t >= 2 && t <= NT + 1), doY = (t >= 3);
    // Phase A: L1(t)+L2(t-1) mains || GMM(t-2) aux<8 | yepi(t-3) aux>=8
    if (w < NMAIN) {
      if (doL1)  mfma_layer<0, 19, 3>(P, af1, scr, gsum, bcl, w, t,     c1,
                                      P.H1H + (size_t)(t & 3)*HSLOT);
      if (doL23) mfma_layer<1, 33, 5>(P, af2, scr, gsum, bcl, w, t - 1, c2,
                                      P.H2H + (size_t)((t - 1) & 1)*HSLOT);
    } else {
      const int q = w - NMAIN;
      if (q < 8) {
        if (doG) gmm_mfma(P, afg, scrg, bgl, q*16, t - 2);
      } else if (doY) {
        const float* gy = P.GY + (size_t)((t - 3) & 1)*GYSLOT;
        for (int yb = ylo; yb < yhi; ++yb)
          yepi_do(P, gy, rawl, smx, yb, t - 3);
      }
    }
    tbar(P.CNT, w, ph);
    // Phase B: L3(t-1) mains || att(t) aux
    if (w < NMAIN) {
      if (doL23) mfma_layer<2, 47, 6>(P, af3, scr, gsum, bcl, w, t - 1, c3,
                                      P.H3H + (size_t)((t - 1) & 1)*HSLOT);
    } else {
      if (doL1)
        for (int lb = 0; lb < bhi - blo; ++lb)
          att_do(P, WAPH, h1p, parts, abk, kapl, phi, winl, batl, csl, cll, blo + lb, lb, t);
    }
    tbar(P.CNT, w, ph);
  }
}

extern "C" void kernel_launch(void* const* d_in, const int* in_sizes, int n_in,
                              void* d_out, int out_size, void* d_ws, size_t ws_size,
                              hipStream_t stream) {
  (void)in_sizes; (void)n_in; (void)out_size; (void)ws_size;
  Params P;
  P.x    = (const float*)d_in[0];
  P.cs   = (const int*)d_in[1];
  P.cl   = (const int*)d_in[2];
  P.bias = (const float*)d_in[3];
  P.Wih1 = (const float*)d_in[4];  P.Whh1 = (const float*)d_in[5];
  P.bih1 = (const float*)d_in[6];  P.bhh1 = (const float*)d_in[7];
  P.Wih2 = (const float*)d_in[8];  P.Whh2 = (const float*)d_in[9];
  P.bih2 = (const float*)d_in[10]; P.bhh2 = (const float*)d_in[11];
  P.Wih3 = (const float*)d_in[12]; P.Whh3 = (const float*)d_in[13];
  P.bih3 = (const float*)d_in[14]; P.bhh3 = (const float*)d_in[15];
  P.Watt = (const float*)d_in[16]; P.batt = (const float*)d_in[17];
  P.Wgmm = (const float*)d_in[18]; P.bgmm = (const float*)d_in[19];
  char* ws = (char*)d_ws;
  P.XTH  = (_Float16*)(ws + OFF_XTH);
  P.H1H  = (_Float16*)(ws + OFF_H1H);
  P.H2H  = (_Float16*)(ws + OFF_H2H);
  P.H3H  = (_Float16*)(ws + OFF_H3H);
  P.WINH = (_Float16*)(ws + OFF_WINH);
  P.BC   = (float*)(ws + OFF_BC);
  P.GY   = (float*)(ws + OFF_GY);
  P.CNT  = (int*)(ws + OFF_CNT);
  P.out  = (float*)d_out;

  hipLaunchKernelGGL(prep_k, dim3(1024), dim3(256), 0, stream, P);
  hipLaunchKernelGGL(rnn_pers, dim3(NWG), dim3(512), 0, stream, P);
}

// Round 14
// 13687.326 us; speedup vs baseline: 2.2989x; 1.0631x over previous
//
#include <hip/hip_runtime.h>
#include <stdint.h>

#define NT 600
#define NMAIN 100
#define NWG 156
#define NAUX (NWG - NMAIN)

// ---- ws layout (bytes) ----
#define OFF_XTH  0          // [600][64][32]  f16  2457600
#define OFF_H1H  2457600    // [4][64][448]   f16  229376
#define OFF_H2H  2686976    // [2][64][448]   f16  114688
#define OFF_H3H  2801664    // [2][64][448]   f16  114688
#define OFF_WINH 2916352    // [2][64][128]   f16  32768
#define OFF_BC   2949120    // [3][1600]      f32  19200
#define OFF_GY   2968320    // [2][64][128]   f32  65536
#define OFF_CNT  3033856    // [12*32]        i32  2048

#define HROW 448
#define HSLOT 28672
#define WROW 128
#define WSLOT 8192
#define XROW 32
#define GYSLOT 8192

typedef _Float16 h2v __attribute__((ext_vector_type(2)));
typedef _Float16 f16x8 __attribute__((ext_vector_type(8)));
typedef float f32x4 __attribute__((ext_vector_type(4)));
typedef unsigned u32x4 __attribute__((ext_vector_type(4)));

struct Params {
  const float* x; const int* cs; const int* cl; const float* bias;
  const float *Wih1,*Whh1,*bih1,*bhh1,*Wih2,*Whh2,*bih2,*bhh2,*Wih3,*Whh3,*bih3,*bhh3;
  const float *Watt,*batt,*Wgmm,*bgmm;
  _Float16 *XTH,*H1H,*H2H,*H3H,*WINH;
  float *BC,*GY;
  int *CNT;
  float* out;
};

__device__ __forceinline__ float sigm(float x) { return 1.f / (1.f + expf(-x)); }

__device__ __forceinline__ float FDOT2(unsigned a, unsigned b, float c) {
#if __has_builtin(__builtin_amdgcn_fdot2)
  return __builtin_amdgcn_fdot2(__builtin_bit_cast(h2v, a), __builtin_bit_cast(h2v, b), c, false);
#else
  h2v x = __builtin_bit_cast(h2v, a), y = __builtin_bit_cast(h2v, b);
  return c + (float)x[0]*(float)y[0] + (float)x[1]*(float)y[1];
#endif
}

// relaxed agent-scope 4B accessors (sc0 sc1 -> LLC write-through / coherent read)
__device__ __forceinline__ unsigned ALu(const void* p) {
  return __hip_atomic_load((const unsigned*)p, __ATOMIC_RELAXED, __HIP_MEMORY_SCOPE_AGENT);
}
__device__ __forceinline__ float ALf(const void* p) {
  return __hip_atomic_load((const float*)p, __ATOMIC_RELAXED, __HIP_MEMORY_SCOPE_AGENT);
}
__device__ __forceinline__ void ASu(void* p, unsigned v) {
  __hip_atomic_store((unsigned*)p, v, __ATOMIC_RELAXED, __HIP_MEMORY_SCOPE_AGENT);
}
__device__ __forceinline__ void ASf(void* p, float v) {
  __hip_atomic_store((float*)p, v, __ATOMIC_RELAXED, __HIP_MEMORY_SCOPE_AGENT);
}

// issue one LLC-coherent 16B load WITHOUT waiting (latency overlapped across all issues)
__device__ __forceinline__ void ld16_issue(const _Float16* p, u32x4& r) {
  asm volatile("global_load_dwordx4 %0, %1, off sc0 sc1"
               : "=v"(r) : "v"(p) : "memory");
}
// drain all outstanding loads, then pin scheduling (rule-18 fence)
__device__ __forceinline__ void ld_drain() {
  asm volatile("s_waitcnt vmcnt(0)" ::: "memory");
  __builtin_amdgcn_sched_barrier(0);
}

// 12-sub-counter barrier, ALL RELAXED (no wbl2/buffer_inv)
__device__ __forceinline__ void tbar(int* C, int w, int& ph) {
  __syncthreads();
  if (threadIdx.x == 0)
    __hip_atomic_fetch_add(&C[(w % 12)*32], 1, __ATOMIC_RELAXED, __HIP_MEMORY_SCOPE_AGENT);
  ++ph;
  const int tgt = 13*ph;
  if (threadIdx.x < 12) {
    while (__hip_atomic_load(&C[threadIdx.x*32], __ATOMIC_RELAXED, __HIP_MEMORY_SCOPE_AGENT) < tgt)
      __builtin_amdgcn_s_sleep(1);
  }
  __syncthreads();
}

// =====================  prep  =====================
__global__ void prep_k(Params P) {
  const long long NX  = 600LL*64*32;
  const long long NH1 = 4LL*64*448;
  const long long NH2 = 2LL*64*448;
  const long long NWH = 2LL*64*128;
  const long long NBc = 4800;
  const long long NCt = 512;
  const long long TOT = NX + NH1 + 2*NH2 + NWH + NBc + NCt;
  const long long stride = (long long)gridDim.x * blockDim.x;
  for (long long idx = (long long)blockIdx.x*blockDim.x + threadIdx.x; idx < TOT; idx += stride) {
    long long i = idx;
    if (i < NX) {
      int t = (int)(i >> 11);
      int rem = (int)(i & 2047);
      int b = rem >> 5, k = rem & 31;
      float v = (k < 3) ? P.x[((size_t)b*NT + t)*3 + k] : 0.f;
      P.XTH[i] = (_Float16)v;
      continue;
    }
    i -= NX;
    if (i < NH1) { P.H1H[i] = (_Float16)0.f; continue; } i -= NH1;
    if (i < NH2) { P.H2H[i] = (_Float16)0.f; continue; } i -= NH2;
    if (i < NH2) { P.H3H[i] = (_Float16)0.f; continue; } i -= NH2;
    if (i < NWH) { P.WINH[i] = (_Float16)0.f; continue; } i -= NWH;
    if (i < NBc) {
      int l = (int)(i / 1600), r = (int)(i % 1600);
      const float* bi = (l==0)?P.bih1:(l==1)?P.bih2:P.bih3;
      const float* bh = (l==0)?P.bhh1:(l==1)?P.bhh2:P.bhh3;
      P.BC[i] = bi[r] + bh[r];
      continue;
    }
    i -= NBc;
    P.CNT[i] = 0;
  }
}

// =====================  MFMA LSTM layer =====================
template<int L, int NBLK, int MAXI>
__device__ __forceinline__ void mfma_layer(const Params& P, const u32x4* af,
    float* scr, float* gsum, const float* bcl, int w, int tt, float& cref, _Float16* Hout) {
  const int tid = threadIdx.x, ks = tid >> 6, l = tid & 63;
  u32x4 bf[MAXI][4];
#pragma unroll
  for (int i = 0; i < MAXI; ++i) {
    const int kb = ks + 8*i;
    if (kb < NBLK) {
      const _Float16* bp; int k0, st; bool isx = false;
      if constexpr (L == 0) {
        if (kb < 4)       { bp = P.WINH + (size_t)((tt+1)&1)*WSLOT; st = WROW; k0 = kb*32; }
        else if (kb == 4) { bp = P.XTH + (size_t)tt*2048;           st = XROW; k0 = 0; isx = true; }
        else              { bp = P.H1H + (size_t)((tt+3)&3)*HSLOT;  st = HROW; k0 = (kb-5)*32; }
      } else if constexpr (L == 1) {
        if (kb == 0)      { bp = P.XTH + (size_t)tt*2048;           st = XROW; k0 = 0; isx = true; }
        else if (kb < 15) { bp = P.H1H + (size_t)(tt&3)*HSLOT;      st = HROW; k0 = (kb-1)*32; }
        else if (kb < 29) { bp = P.H2H + (size_t)((tt+1)&1)*HSLOT;  st = HROW; k0 = (kb-15)*32; }
        else              { bp = P.WINH + (size_t)(tt&1)*WSLOT;     st = WROW; k0 = (kb-29)*32; }
      } else {
        if (kb == 0)      { bp = P.XTH + (size_t)tt*2048;           st = XROW; k0 = 0; isx = true; }
        else if (kb < 15) { bp = P.H1H + (size_t)(tt&3)*HSLOT;      st = HROW; k0 = (kb-1)*32; }
        else if (kb < 29) { bp = P.H3H + (size_t)((tt+1)&1)*HSLOT;  st = HROW; k0 = (kb-15)*32; }
        else if (kb < 43) { bp = P.H2H + (size_t)(tt&1)*HSLOT;      st = HROW; k0 = (kb-29)*32; }
        else              { bp = P.WINH + (size_t)(tt&1)*WSLOT;     st = WROW; k0 = (kb-43)*32; }
      }
      const _Float16* base = bp + (size_t)(l & 15)*st + k0 + ((l >> 4)*8);
      if (isx) {
#pragma unroll
        for (int ct = 0; ct < 4; ++ct)
          bf[i][ct] = *(const u32x4*)(base + (size_t)ct*16*st);
      } else {
#pragma unroll
        for (int ct = 0; ct < 4; ++ct)
          ld16_issue(base + (size_t)ct*16*st, bf[i][ct]);
      }
    }
  }
  ld_drain();   // single wait for ALL outstanding state loads of this layer
  f32x4 acc[4] = {{0.f,0.f,0.f,0.f},{0.f,0.f,0.f,0.f},{0.f,0.f,0.f,0.f},{0.f,0.f,0.f,0.f}};
#pragma unroll
  for (int i = 0; i < MAXI; ++i) {
    const int kb = ks + 8*i;
    if (kb < NBLK) {
#pragma unroll
      for (int ct = 0; ct < 4; ++ct)
        acc[ct] = __builtin_amdgcn_mfma_f32_16x16x32_f16(
            __builtin_bit_cast(f16x8, af[i]), __builtin_bit_cast(f16x8, bf[i][ct]),
            acc[ct], 0, 0, 0);
    }
  }
  __syncthreads();
#pragma unroll
  for (int ct = 0; ct < 4; ++ct)
    *(f32x4*)&scr[((size_t)(ks*64 + ct*16 + (l & 15)))*21 + (l >> 4)*4] = acc[ct];
  __syncthreads();
#pragma unroll
  for (int p = 0; p < 2; ++p) {
    const int idx = tid + p*512, m = idx >> 6, b = idx & 63;
    float s = 0.f;
#pragma unroll
    for (int k = 0; k < 8; ++k) s += scr[(size_t)(k*64 + b)*21 + m];
    gsum[b*21 + m] = s + bcl[L*16 + m];
  }
  __syncthreads();
  if (tid < 256) {
    const int dd = tid >> 6, b = tid & 63;
    const float* gp = gsum + b*21 + dd*4;
    float c = sigm(gp[1])*cref + sigm(gp[0])*tanhf(gp[2]);
    cref = c;
    float h = sigm(gp[3])*tanhf(c);
    gsum[b*21 + 16 + dd] = h;           // stage for paired u32 store
  }
  __syncthreads();
  if (tid < 128) {
    const int d2 = tid >> 6, b = tid & 63;      // d2 = 0,1 -> dims (2*d2, 2*d2+1)
    _Float16 lo = (_Float16)gsum[b*21 + 16 + 2*d2];
    _Float16 hi = (_Float16)gsum[b*21 + 16 + 2*d2 + 1];
    h2v pk = { lo, hi };
    ASu(Hout + (size_t)b*HROW + 4*w + 2*d2, __builtin_bit_cast(unsigned, pk));
  }
}

// =====================  GMM via MFMA  =====================
__device__ __forceinline__ void gmm_mfma(const Params& P, const u32x4* afg,
    float* scr, const float* bgl, int rlo, int tt) {
  const int tid = threadIdx.x, ks = tid >> 6, l = tid & 63;
  const _Float16* h1 = P.H1H + (size_t)(tt & 3)*HSLOT;
  const _Float16* h2 = P.H2H + (size_t)(tt & 1)*HSLOT;
  const _Float16* h3 = P.H3H + (size_t)(tt & 1)*HSLOT;
  u32x4 bf[6][4];
#pragma unroll
  for (int i = 0; i < 6; ++i) {
    const int kb = ks + 8*i;
    if (kb < 42) {
      const _Float16* bp; int k0;
      if (kb < 14)      { bp = h1; k0 = kb*32; }
      else if (kb < 28) { bp = h2; k0 = (kb-14)*32; }
      else              { bp = h3; k0 = (kb-28)*32; }
      const _Float16* base = bp + (size_t)(l & 15)*HROW + k0 + ((l >> 4)*8);
#pragma unroll
      for (int ct = 0; ct < 4; ++ct)
        ld16_issue(base + (size_t)ct*16*HROW, bf[i][ct]);
    }
  }
  ld_drain();
  f32x4 acc[4] = {{0.f,0.f,0.f,0.f},{0.f,0.f,0.f,0.f},{0.f,0.f,0.f,0.f},{0.f,0.f,0.f,0.f}};
#pragma unroll
  for (int i = 0; i < 6; ++i) {
    const int kb = ks + 8*i;
    if (kb < 42) {
#pragma unroll
      for (int ct = 0; ct < 4; ++ct)
        acc[ct] = __builtin_amdgcn_mfma_f32_16x16x32_f16(
            __builtin_bit_cast(f16x8, afg[i]), __builtin_bit_cast(f16x8, bf[i][ct]),
            acc[ct], 0, 0, 0);
    }
  }
  __syncthreads();
#pragma unroll
  for (int ct = 0; ct < 4; ++ct)
    *(f32x4*)&scr[((size_t)(ks*64 + ct*16 + (l & 15)))*17 + (l >> 4)*4] = acc[ct];
  __syncthreads();
  float* gy = P.GY + (size_t)(tt & 1)*GYSLOT;
#pragma unroll
  for (int p = 0; p < 2; ++p) {
    const int idx = tid + p*512, m = idx >> 6, b = idx & 63;
    float s = 0.f;
#pragma unroll
    for (int k = 0; k < 8; ++k) s += scr[(size_t)(k*64 + b)*17 + m];
    const int r = rlo + m;
    if (r < 121) ASf(&gy[b*128 + r], s + bgl[m]);
  }
  __syncthreads();
}

// attention window
__device__ __forceinline__ void att_do(const Params& P, const unsigned* WAPH, unsigned* h1p,
    float* parts, float* abk, float* kapl, float* phi, float* winl,
    const float* batl, const int* csl, const int* cll, int b, int lb, int t) {
  const int tid = threadIdx.x;
  const int s1 = t & 3, sw = t & 1;
  if (tid < 224)
    h1p[tid] = ALu((const unsigned*)(P.H1H + (size_t)s1*HSLOT + (size_t)b*HROW) + tid);
  __syncthreads();
  if (tid < 240) {
    int j = tid >> 3, pp = tid & 7;
    const unsigned* wr = WAPH + j*200 + pp*25;
    const unsigned* hr = h1p + pp*25;
    float acc = 0.f;
#pragma unroll
    for (int m = 0; m < 25; ++m) acc = FDOT2(hr[m], wr[m], acc);
    parts[tid] = acc;
  }
  __syncthreads();
  if (tid < 30) {
    float s = batl[tid];
#pragma unroll
    for (int pp = 0; pp < 8; ++pp) s += parts[tid*8 + pp];
    abk[tid] = expf(s);
  }
  __syncthreads();
  if (tid < 10) kapl[lb*10 + tid] += abk[20 + tid];
  __syncthreads();
  if (tid < 50) {
    float s = 0.f;
    if (tid < cll[lb]) {
#pragma unroll
      for (int k = 0; k < 10; ++k) {
        float dk = kapl[lb*10 + k] - (float)tid;
        s += abk[k]*expf(-abk[10 + k]*dk*dk);
      }
    }
    phi[tid] = s;
  }
  __syncthreads();
  if (tid < 77) {
    float s = 0.f;
    for (int u = 0; u < 50; ++u) s += (csl[lb*50 + u] == tid) ? phi[u] : 0.f;
    winl[tid] = s;
  }
  __syncthreads();
  if (tid < 64) {
    int a0 = 2*tid, a1 = 2*tid + 1;
    h2v pk = { (_Float16)((a0 < 77) ? winl[a0] : 0.f),
               (_Float16)((a1 < 77) ? winl[a1] : 0.f) };
    ASu(P.WINH + (size_t)sw*WSLOT + (size_t)b*WROW + a0, __builtin_bit_cast(unsigned, pk));
  }
  __syncthreads();
}

// y epilogue
__device__ __forceinline__ void yepi_do(const Params& P, const float* gy,
                                        float* rawl, float* smx, int b, int tt) {
  const int tid = threadIdx.x;
  __syncthreads();
  if (tid < 121) rawl[tid] = ALf(&gy[b*128 + tid]);
  __syncthreads();
  const float bia = P.bias[b];
  if (tid == 0) {
    float m = -1e30f;
    for (int j = 1; j <= 20; ++j) m = fmaxf(m, rawl[j]*(1.f + bia));
    float ss = 0.f;
    for (int j = 1; j <= 20; ++j) ss += expf(rawl[j]*(1.f + bia) - m);
    smx[0] = m; smx[1] = ss;
  }
  __syncthreads();
  float* yr = P.out + ((size_t)b*NT + tt)*121;
  if (tid == 0)           yr[120] = 1.f/(1.f + expf(-rawl[0]));
  else if (tid <= 20)     yr[tid - 1] = expf(rawl[tid]*(1.f + bia) - smx[0]) / smx[1];
  else if (tid <= 60)     yr[80 + tid - 21] = rawl[tid];
  else if (tid <= 100)    yr[20 + tid - 61] = expf(rawl[tid] - bia);
  else if (tid <= 120)    yr[60 + tid - 101] = tanhf(rawl[tid]);
  __syncthreads();
}

// =====================  persistent kernel: 156 WGs x 512 threads  =====================
__global__ __launch_bounds__(512, 1) void rnn_pers(Params P) {
  __shared__ __align__(16) char smem[69888];
  float* scr  = (float*)smem;                  // [8][64][21] f32
  float* gsum = (float*)(smem + 43008);        // [64][21] f32
  float* bcl  = (float*)(smem + 48384);        // 48 f32
  float* scrg = (float*)smem;                  // [8][64][17] f32 (aux q<8)
  unsigned* WAPH = (unsigned*)(smem + 39168);  // aux: Watt f16 pairs [30][200]
  float* M    = (float*)(smem + 63168);
  float* bgl  = M;
  float* parts= M + 16;
  float* abk  = M + 256;
  float* kapl = M + 286;
  float* phi  = M + 306;
  float* winl = M + 356;
  float* batl = M + 436;
  float* rawl = M + 466;
  float* smx  = M + 587;
  unsigned* h1p = (unsigned*)(M + 589);
  int*   csl  = (int*)(M + 813);
  int*   cll  = (int*)(M + 913);

  const int w = blockIdx.x, tid = threadIdx.x;
  const int ks = tid >> 6, l = tid & 63;
  int blo = 0, bhi = 0, ylo = 0, yhi = 0;
  u32x4 af1[3], af2[5], af3[6], afg[6];

  if (w < NMAIN) {
    const int m = l & 15, dd = m >> 2, g = m & 3, gr = g*400 + 4*w + dd;
    const int kgo = (l >> 4)*8;
#pragma unroll
    for (int i = 0; i < 3; ++i) {
      const int kb = ks + 8*i;
      unsigned short u[8];
#pragma unroll
      for (int j = 0; j < 8; ++j) {
        float v = 0.f;
        if (kb < 19) {
          int kk = kb*32 + kgo + j;
          if (kk < 128)      { if (kk < 77) v = P.Wih1[(size_t)gr*80 + kk]; }
          else if (kk < 160) { int c = kk - 128; if (c < 3) v = P.Wih1[(size_t)gr*80 + 77 + c]; }
          else               { int c = kk - 160; if (c < 400) v = P.Whh1[(size_t)gr*400 + c]; }
        }
        u[j] = __builtin_bit_cast(unsigned short, (_Float16)v);
      }
      af1[i] = (u32x4){(unsigned)u[0]|((unsigned)u[1]<<16), (unsigned)u[2]|((unsigned)u[3]<<16),
                       (unsigned)u[4]|((unsigned)u[5]<<16), (unsigned)u[6]|((unsigned)u[7]<<16)};
    }
#pragma unroll
    for (int i = 0; i < 5; ++i) {
      const int kb = ks + 8*i;
      unsigned short u[8];
#pragma unroll
      for (int j = 0; j < 8; ++j) {
        float v = 0.f;
        if (kb < 33) {
          int kk = kb*32 + kgo + j;
          if (kk < 32)       { if (kk < 3) v = P.Wih2[(size_t)gr*480 + kk]; }
          else if (kk < 480) { int c = kk - 32;  if (c < 400) v = P.Wih2[(size_t)gr*480 + 3 + c]; }
          else if (kk < 928) { int c = kk - 480; if (c < 400) v = P.Whh2[(size_t)gr*400 + c]; }
          else               { int c = kk - 928; if (c < 77)  v = P.Wih2[(size_t)gr*480 + 403 + c]; }
        }
        u[j] = __builtin_bit_cast(unsigned short, (_Float16)v);
      }
      af2[i] = (u32x4){(unsigned)u[0]|((unsigned)u[1]<<16), (unsigned)u[2]|((unsigned)u[3]<<16),
                       (unsigned)u[4]|((unsigned)u[5]<<16), (unsigned)u[6]|((unsigned)u[7]<<16)};
    }
#pragma unroll
    for (int i = 0; i < 6; ++i) {
      const int kb = ks + 8*i;
      unsigned short u[8];
#pragma unroll
      for (int j = 0; j < 8; ++j) {
        float v = 0.f;
        if (kb < 47) {
          int kk = kb*32 + kgo + j;
          if (kk < 32)        { if (kk < 3) v = P.Wih3[(size_t)gr*880 + kk]; }
          else if (kk < 480)  { int c = kk - 32;   if (c < 400) v = P.Wih3[(size_t)gr*880 + 3 + c]; }
          else if (kk < 928)  { int c = kk - 480;  if (c < 400) v = P.Whh3[(size_t)gr*400 + c]; }
          else if (kk < 1376) { int c = kk - 928;  if (c < 400) v = P.Wih3[(size_t)gr*880 + 403 + c]; }
          else                { int c = kk - 1376; if (c < 77)  v = P.Wih3[(size_t)gr*880 + 803 + c]; }
        }
        u[j] = __builtin_bit_cast(unsigned short, (_Float16)v);
      }
      af3[i] = (u32x4){(unsigned)u[0]|((unsigned)u[1]<<16), (unsigned)u[2]|((unsigned)u[3]<<16),
                       (unsigned)u[4]|((unsigned)u[5]<<16), (unsigned)u[6]|((unsigned)u[7]<<16)};
    }
    if (tid < 48) {
      int L = tid >> 4, mm = tid & 15, ddb = mm >> 2, gb = mm & 3;
      bcl[tid] = P.BC[L*1600 + gb*400 + 4*w + ddb];
    }
  } else {
    const int q = w - NMAIN;
    blo = (64*q)/NAUX;  bhi = (64*(q+1))/NAUX;
    if (q >= 8) { ylo = (64*(q-8))/48; yhi = (64*(q-7))/48; }
    if (q < 8) {
      const int m = l & 15, gr = q*16 + m;
      const int kgo = (l >> 4)*8;
#pragma unroll
      for (int i = 0; i < 6; ++i) {
        const int kb = ks + 8*i;
        unsigned short u[8];
#pragma unroll
        for (int j = 0; j < 8; ++j) {
          float v = 0.f;
          if (kb < 42 && gr < 121) {
            int kk = kb*32 + kgo + j;
            if (kk < 448)      { if (kk < 400) v = P.Wgmm[(size_t)gr*1200 + kk]; }
            else if (kk < 896) { int c = kk - 448; if (c < 400) v = P.Wgmm[(size_t)gr*1200 + 400 + c]; }
            else               { int c = kk - 896; if (c < 400) v = P.Wgmm[(size_t)gr*1200 + 800 + c]; }
          }
          u[j] = __builtin_bit_cast(unsigned short, (_Float16)v);
        }
        afg[i] = (u32x4){(unsigned)u[0]|((unsigned)u[1]<<16), (unsigned)u[2]|((unsigned)u[3]<<16),
                         (unsigned)u[4]|((unsigned)u[5]<<16), (unsigned)u[6]|((unsigned)u[7]<<16)};
      }
      if (tid < 16) bgl[tid] = (q*16 + tid < 121) ? P.bgmm[q*16 + tid] : 0.f;
    }
    for (int i = tid; i < 6000; i += 512) {
      int j = i / 200, pr = i % 200;
      h2v pk = { (_Float16)P.Watt[j*400 + 2*pr], (_Float16)P.Watt[j*400 + 2*pr + 1] };
      WAPH[i] = __builtin_bit_cast(unsigned, pk);
    }
    if (tid < 30) batl[tid] = P.batt[tid];
    for (int lb = 0; lb < bhi - blo; ++lb) {
      if (tid < 50) csl[lb*50 + tid] = P.cs[(blo + lb)*50 + tid];
      if (tid == 0) cll[lb] = P.cl[blo + lb];
    }
    if (tid < 20) kapl[tid] = 0.f;
  }
  __syncthreads();

  int ph = 0;
  float c1 = 0.f, c2 = 0.f, c3 = 0.f;
  for (int t = 0; t <= NT + 2; ++t) {
    const bool doL1 = (t < NT), doL23 = (t >= 1 && t <= NT);
    const bool doG = (t >= 2 && t <= NT + 1), doY = (t >= 3);
    // Phase A: L1(t)+L2(t-1) mains || GMM(t-2) aux<8 | yepi(t-3) aux>=8
    if (w < NMAIN) {
      if (doL1)  mfma_layer<0, 19, 3>(P, af1, scr, gsum, bcl, w, t,     c1,
                                      P.H1H + (size_t)(t & 3)*HSLOT);
      if (doL23) mfma_layer<1, 33, 5>(P, af2, scr, gsum, bcl, w, t - 1, c2,
                                      P.H2H + (size_t)((t - 1) & 1)*HSLOT);
    } else {
      const int q = w - NMAIN;
      if (q < 8) {
        if (doG) gmm_mfma(P, afg, scrg, bgl, q*16, t - 2);
      } else if (doY) {
        const float* gy = P.GY + (size_t)((t - 3) & 1)*GYSLOT;
        for (int yb = ylo; yb < yhi; ++yb)
          yepi_do(P, gy, rawl, smx, yb, t - 3);
      }
    }
    tbar(P.CNT, w, ph);
    // Phase B: L3(t-1) mains || att(t) aux
    if (w < NMAIN) {
      if (doL23) mfma_layer<2, 47, 6>(P, af3, scr, gsum, bcl, w, t - 1, c3,
                                      P.H3H + (size_t)((t - 1) & 1)*HSLOT);
    } else {
      if (doL1)
        for (int lb = 0; lb < bhi - blo; ++lb)
          att_do(P, WAPH, h1p, parts, abk, kapl, phi, winl, batl, csl, cll, blo + lb, lb, t);
    }
    tbar(P.CNT, w, ph);
  }
}

extern "C" void kernel_launch(void* const* d_in, const int* in_sizes, int n_in,
                              void* d_out, int out_size, void* d_ws, size_t ws_size,
                              hipStream_t stream) {
  (void)in_sizes; (void)n_in; (void)out_size; (void)ws_size;
  Params P;
  P.x    = (const float*)d_in[0];
  P.cs   = (const int*)d_in[1];
  P.cl   = (const int*)d_in[2];
  P.bias = (const float*)d_in[3];
  P.Wih1 = (const float*)d_in[4];  P.Whh1 = (const float*)d_in[5];
  P.bih1 = (const float*)d_in[6];  P.bhh1 = (const float*)d_in[7];
  P.Wih2 = (const float*)d_in[8];  P.Whh2 = (const float*)d_in[9];
  P.bih2 = (const float*)d_in[10]; P.bhh2 = (const float*)d_in[11];
  P.Wih3 = (const float*)d_in[12]; P.Whh3 = (const float*)d_in[13];
  P.bih3 = (const float*)d_in[14]; P.bhh3 = (const float*)d_in[15];
  P.Watt = (const float*)d_in[16]; P.batt = (const float*)d_in[17];
  P.Wgmm = (const float*)d_in[18]; P.bgmm = (const float*)d_in[19];
  char* ws = (char*)d_ws;
  P.XTH  = (_Float16*)(ws + OFF_XTH);
  P.H1H  = (_Float16*)(ws + OFF_H1H);
  P.H2H  = (_Float16*)(ws + OFF_H2H);
  P.H3H  = (_Float16*)(ws + OFF_H3H);
  P.WINH = (_Float16*)(ws + OFF_WINH);
  P.BC   = (float*)(ws + OFF_BC);
  P.GY   = (float*)(ws + OFF_GY);
  P.CNT  = (int*)(ws + OFF_CNT);
  P.out  = (float*)d_out;

  hipLaunchKernelGGL(prep_k, dim3(1024), dim3(256), 0, stream, P);
  hipLaunchKernelGGL(rnn_pers, dim3(NWG), dim3(512), 0, stream, P);
}